// Round 2
// baseline (1422.021 us; speedup 1.0000x reference)
//
#include <hip/hip_runtime.h>

// ============================================================================
// MYLSTM round 2: weight-stationary cooperative recurrent kernel.
//  - 256 wgs x 512 thr, cooperative launch, 1 wg/CU (143 KB dynamic LDS).
//  - wg (i = bid>>3, j = bid&7): batch rows b0=i*64 (64 rows), units u0=j*32.
//  - Gate weights Wc slice (128 cols x 256 k bf16 = 64 KB) resident in LDS
//    for all 49 steps -> kills the 1.29 GB HBM weight thrash of round 1.
//  - Per step: stage cB rows -> LDS, gate MFMA (K=256), elementwise (c in
//    LDS fp32), write cB/sB bf16 (double-buffered) to global, 8-wg barrier
//    (device-scope atomics; exchange is row-group-local), stage sB, proj MFMA
//    vs U_t (streamed from L2/L3), tanh -> out.
//  - xp = x @ Wx precomputed by xproj2 (112 rows/wg); pack_u2 reads Q once.
// ============================================================================

typedef unsigned short u16;
typedef unsigned int u32;
typedef __attribute__((ext_vector_type(8))) short bf16x8;
typedef __attribute__((ext_vector_type(4))) float f32x4;

#define T_STEPS 49
#define OUT_ROW 12544        // 49*256
#define NWG 256
#define GRPWG 8              // wgs per row-group (share batch rows)
#define SMEM_BYTES 143360

__device__ __forceinline__ u16 f2b(float f) {
  u32 u = __float_as_uint(f);
  u += 0x7fffu + ((u >> 16) & 1u); // RNE
  return (u16)(u >> 16);
}
__device__ __forceinline__ float b2f(u16 h) { return __uint_as_float(((u32)h) << 16); }
__device__ __forceinline__ float sigm(float z) { return 1.0f / (1.0f + __expf(-z)); }
__device__ __forceinline__ float tanh_f(float z) {
  float e = __expf(-2.0f * fabsf(z));
  float r = (1.0f - e) / (1.0f + e);
  return __builtin_copysignf(r, z);
}

// ---------------------------------------------------------------------------
__global__ void init_bar(int* __restrict__ bar) {
  int i = blockIdx.x * 512 + threadIdx.x;
  if (i < 2048) bar[i] = 0;
}

// ---------------------------------------------------------------------------
// Pack weights: WcP[n][k] = W_g[k][u], WxP[n][k] = W_g[256+k][u]; n=g*256+u.
__global__ void pack_w(const float* __restrict__ Wf, const float* __restrict__ Wi,
                       const float* __restrict__ Wc, const float* __restrict__ Wo,
                       u16* __restrict__ WcP, u16* __restrict__ WxP) {
  int n = blockIdx.x, k = threadIdx.x;
  int g = n >> 8, u = n & 255;
  const float* W = (g == 0) ? Wf : (g == 1) ? Wi : (g == 2) ? Wc : Wo;
  WcP[n * 256 + k] = f2b(W[k * 256 + u]);
  WxP[n * 256 + k] = f2b(W[(256 + k) * 256 + u]);
}

// ---------------------------------------------------------------------------
// U pack, Q read ONCE per thread (round-1 version re-read Q 49x = 1.16 GB).
// grid 256 blocks (jp) x 256 thr (j).
__global__ void pack_u2(const float* __restrict__ Q, u16* __restrict__ UP) {
  int jp = blockIdx.x, j = threadIdx.x;
  float q[9];
#pragma unroll
  for (int k = 0; k < 9; ++k) q[k] = Q[j * 2304 + jp * 9 + k];
  const float SQ2 = 1.41421356237f;
  for (int t = 0; t < T_STEPS; ++t) {
    float tv = (float)t / 48.0f;
    float acc = q[0];
#pragma unroll
    for (int i = 1; i <= 4; ++i) {
      float ang = 6.283185307179586f * (float)i * tv;
      acc += SQ2 * (sinf(ang) * q[2 * i - 1] + cosf(ang) * q[2 * i]);
    }
    UP[t * 65536 + jp * 256 + j] = f2b(acc);
  }
}

// ---------------------------------------------------------------------------
// xproj: xp[m][n] = x_row(m) @ WxP[n][:], m = b*49+t (x is contiguous in m).
// 112 rows/wg (vs 64 in round 1): halves per-row B traffic. grid 896 x 256.
__global__ __launch_bounds__(256) void xproj2(const float* __restrict__ x,
                                              const u16* __restrict__ WxP,
                                              u16* __restrict__ xp) {
  __shared__ u16 aLds[112][264]; // 59136 B, +8 pad -> 2-way banks only
  int tid = threadIdx.x;
  int m0 = blockIdx.x * 112;
  // stage: 112 rows x 256 fp32 -> bf16. x row m is at x + m*256 (m=b*49+t).
#pragma unroll
  for (int it = 0; it < 28; ++it) {
    int flat = (it * 256 + tid) * 16; // bytes in fp32 space
    int r = flat >> 10, k = (flat & 1023) >> 2;
    float4 v = *(const float4*)&x[(size_t)(m0 + r) * 256 + k];
    u16 tmp[4] = {f2b(v.x), f2b(v.y), f2b(v.z), f2b(v.w)};
    *(uint2*)&aLds[r][k] = *(uint2*)tmp;
  }
  __syncthreads();
  int w = tid >> 6, l = tid & 63, l15 = l & 15, quad = l >> 4;
  for (int ct = 0; ct < 16; ++ct) {
    int col = w * 256 + ct * 16 + l15;
    bf16x8 bf[8];
    const u16* bp = WxP + (size_t)col * 256 + quad * 8;
#pragma unroll
    for (int ks = 0; ks < 8; ++ks) bf[ks] = *(const bf16x8*)(bp + ks * 32);
#pragma unroll
    for (int rt = 0; rt < 7; ++rt) {
      f32x4 acc = {0.f, 0.f, 0.f, 0.f};
#pragma unroll
      for (int ks = 0; ks < 8; ++ks) {
        bf16x8 a = *(const bf16x8*)&aLds[rt * 16 + l15][ks * 32 + quad * 8];
        acc = __builtin_amdgcn_mfma_f32_16x16x32_bf16(a, bf[ks], acc, 0, 0, 0);
      }
#pragma unroll
      for (int ii = 0; ii < 4; ++ii)
        xp[(size_t)(m0 + rt * 16 + quad * 4 + ii) * 1024 + col] = f2b(acc[ii]);
    }
  }
}

// ---------------------------------------------------------------------------
// Row-group-local grid barrier: 8 wgs count up on bar slot, device scope.
__device__ __forceinline__ void gbar(int* slot) {
  __syncthreads();
  if (threadIdx.x == 0) {
    __hip_atomic_fetch_add(slot, 1, __ATOMIC_ACQ_REL, __HIP_MEMORY_SCOPE_AGENT);
    while (__hip_atomic_load(slot, __ATOMIC_ACQUIRE, __HIP_MEMORY_SCOPE_AGENT) < GRPWG)
      __builtin_amdgcn_s_sleep(2);
  }
  __syncthreads();
}

// ---------------------------------------------------------------------------
__global__ __launch_bounds__(512) void rec2(const u16* __restrict__ WcP,
                                            const u16* __restrict__ UP,
                                            const u16* __restrict__ xp,
                                            float* __restrict__ out,
                                            u16* __restrict__ cBg,
                                            u16* __restrict__ sBg,
                                            int* __restrict__ bar) {
  extern __shared__ char smem[];
  u16(*wLds)[264] = (u16(*)[264])smem;                      // 128x264 = 67584 B
  u16(*aStage)[264] = (u16(*)[264])(smem + 67584);          // 64x264  = 33792 B
  float(*Z)[132] = (float(*)[132])(smem + 101376);          // 64x132  = 33792 B
  float(*cF)[32] = (float(*)[32])(smem + 135168);           // 64x32   =  8192 B

  int tid = threadIdx.x;
  int bid = blockIdx.x;
  int i = bid >> 3, j = bid & 7;
  int b0 = i * 64, u0 = j * 32;

  // --- load gate-weight slice into LDS (once): 128 local cols x 256 k.
  // local col c = g*32+uu  <->  global n = g*256 + u0 + uu.
  for (int c = tid; c < 128 * 32; c += 512) { // 16B chunks
    int col = c >> 5, koff = (c & 31) * 8;
    int g = col >> 5, uu = col & 31;
    *(uint4*)&wLds[col][koff] = *(const uint4*)&WcP[(size_t)(g * 256 + u0 + uu) * 256 + koff];
  }
#pragma unroll
  for (int p = 0; p < 4; ++p) {
    int item = tid + p * 512;
    cF[item >> 5][item & 31] = 0.0f;
  }
  __syncthreads();

  int w = tid >> 6, l = tid & 63, l15 = l & 15, quad = l >> 4;
  // hoist this wave's gate B-frags (loop-invariant over t): cols w*16..+15
  bf16x8 bfr[8];
#pragma unroll
  for (int ks = 0; ks < 8; ++ks)
    bfr[ks] = *(const bf16x8*)&wLds[w * 16 + l15][ks * 32 + quad * 8];

  int prt = w >> 1, pct = w & 1; // proj tile assignment

#pragma unroll 1
  for (int t = 0; t < T_STEPS; ++t) {
    int rd = t & 1, wr = (t + 1) & 1;
    // xp prefetch for elementwise (hidden under staging+GEMM)
    float xv[4][4];
#pragma unroll
    for (int p = 0; p < 4; ++p) {
      int item = tid + p * 512, r = item >> 5, uu = item & 31;
      const u16* xb = xp + ((size_t)(b0 + r) * 49 + t) * 1024 + u0 + uu;
#pragma unroll
      for (int g = 0; g < 4; ++g) xv[p][g] = b2f(xb[g * 256]);
    }
    if (t > 0) {
      // stage cB rows b0..b0+63 (32 KB)
#pragma unroll
      for (int it = 0; it < 4; ++it) {
        int flat = (it * 512 + tid) * 16; // bytes
        int r = flat >> 9, off = (flat & 511) >> 1;
        *(uint4*)&aStage[r][off] =
            *(const uint4*)&cBg[(size_t)rd * 524288 + (size_t)(b0 + r) * 256 + off];
      }
      __syncthreads();
      // gate GEMM: wave w -> 16 cols, 4 row-tiles, K=256
#pragma unroll
      for (int rt = 0; rt < 4; ++rt) {
        f32x4 acc = {0.f, 0.f, 0.f, 0.f};
#pragma unroll
        for (int ks = 0; ks < 8; ++ks) {
          bf16x8 a = *(const bf16x8*)&aStage[rt * 16 + l15][ks * 32 + quad * 8];
          acc = __builtin_amdgcn_mfma_f32_16x16x32_bf16(a, bfr[ks], acc, 0, 0, 0);
        }
#pragma unroll
        for (int ii = 0; ii < 4; ++ii) Z[rt * 16 + quad * 4 + ii][w * 16 + l15] = acc[ii];
      }
      __syncthreads();
    }
    // elementwise: 64 rows x 32 units, fp32
#pragma unroll
    for (int p = 0; p < 4; ++p) {
      int item = tid + p * 512, r = item >> 5, uu = item & 31;
      float zf = xv[p][0], zi = xv[p][1], zg = xv[p][2], zo = xv[p][3];
      if (t > 0) {
        zf += Z[r][uu];
        zi += Z[r][32 + uu];
        zg += Z[r][64 + uu];
        zo += Z[r][96 + uu];
      }
      float f = sigm(zf), ig = sigm(zi), gg = sigm(zg), o = tanh_f(zo);
      float cn = ig * gg + f * cF[r][uu];
      cF[r][uu] = cn;
      float s = o * tanh_f(cn);
      size_t gi = (size_t)wr * 524288 + (size_t)(b0 + r) * 256 + u0 + uu;
      cBg[gi] = f2b(cn);
      sBg[gi] = f2b(s);
    }
    // 8-wg row-group barrier (exchange of c/s is group-local)
    gbar(bar + i * 64 + t);
    // stage full s rows (all 256 units) for proj
#pragma unroll
    for (int it = 0; it < 4; ++it) {
      int flat = (it * 512 + tid) * 16;
      int r = flat >> 9, off = (flat & 511) >> 1;
      *(uint4*)&aStage[r][off] =
          *(const uint4*)&sBg[(size_t)wr * 524288 + (size_t)(b0 + r) * 256 + off];
    }
    __syncthreads();
    // proj GEMM: wave w -> (row-tile w>>1, col-tile w&1); B from UP (L2-hot)
    {
      f32x4 acc = {0.f, 0.f, 0.f, 0.f};
      const u16* up = UP + t * 65536 + (size_t)(u0 + pct * 16 + l15) * 256 + quad * 8;
#pragma unroll
      for (int ks = 0; ks < 8; ++ks) {
        bf16x8 a = *(const bf16x8*)&aStage[prt * 16 + l15][ks * 32 + quad * 8];
        bf16x8 b = *(const bf16x8*)(up + ks * 32);
        acc = __builtin_amdgcn_mfma_f32_16x16x32_bf16(a, b, acc, 0, 0, 0);
      }
#pragma unroll
      for (int ii = 0; ii < 4; ++ii)
        out[(size_t)(b0 + prt * 16 + quad * 4 + ii) * OUT_ROW + t * 256 + u0 + pct * 16 + l15] =
            tanh_f(acc[ii]);
    }
    __syncthreads(); // aStage reused by next step's cB staging
  }
}

// ---------------------------------------------------------------------------
extern "C" void kernel_launch(void* const* d_in, const int* in_sizes, int n_in,
                              void* d_out, int out_size, void* d_ws, size_t ws_size,
                              hipStream_t stream) {
  const float* x = (const float*)d_in[0];
  const float* Wf = (const float*)d_in[1];
  const float* Wi = (const float*)d_in[2];
  const float* Wc = (const float*)d_in[3];
  const float* Wo = (const float*)d_in[4];
  const float* Q = (const float*)d_in[5];
  float* out = (float*)d_out;

  char* p = (char*)d_ws;
  u16* WcP = (u16*)p;  p += (size_t)1024 * 256 * 2;        // 512 KB
  u16* WxP = (u16*)p;  p += (size_t)1024 * 256 * 2;        // 512 KB
  u16* UP = (u16*)p;   p += (size_t)49 * 65536 * 2;        // 6.13 MB
  u16* cBg = (u16*)p;  p += (size_t)2 * 524288 * 2;        // 2 MB (dbuf)
  u16* sBg = (u16*)p;  p += (size_t)2 * 524288 * 2;        // 2 MB (dbuf)
  int* bar = (int*)p;  p += 8192;                          // 2048 barrier slots
  u16* xp = (u16*)p;                                       // 205.5 MB

  hipFuncSetAttribute((const void*)rec2, hipFuncAttributeMaxDynamicSharedMemorySize,
                      SMEM_BYTES);

  init_bar<<<dim3(4), dim3(512), 0, stream>>>(bar);
  pack_w<<<dim3(1024), dim3(256), 0, stream>>>(Wf, Wi, Wc, Wo, WcP, WxP);
  pack_u2<<<dim3(256), dim3(256), 0, stream>>>(Q, UP);
  xproj2<<<dim3(896), dim3(256), 0, stream>>>(x, WxP, xp);

  void* args[] = {(void*)&WcP, (void*)&UP, (void*)&xp, (void*)&out,
                  (void*)&cBg, (void*)&sBg, (void*)&bar};
  hipLaunchCooperativeKernel((const void*)rec2, dim3(NWG), dim3(512), args,
                             SMEM_BYTES, stream);
}

// Round 4
// 1372.545 us; speedup vs baseline: 1.0360x; 1.0360x over previous
//
#include <hip/hip_runtime.h>

// ============================================================================
// MYLSTM round 4 = round 3 + one-line fix: xproj3 writeout loop j<4 -> j<8
// (rows 16..31 of each 32-row xp tile were never written -> poison read).
//
// Structure: batch-parallel (communication-free) recurrent kernel with
// T chunked 7x7 for cache locality + partial LDS-resident gate weights.
//  - rec3: 256 wgs x 512 thr; wg owns 8 batch rows for a 7-step chunk.
//    Weights: cols 0..159 of WcP live in LDS (84 KB, loaded once/launch);
//    remaining 864 cols + U_t stream from L2 (chunking keeps them resident).
//    c state in LDS fp32; out written via LDS restage (full-line writes).
//  - xproj3: xp[m][n] = x_row @ Wx, m = b*7+tt chunk-local; 32 rows/wg,
//    512 thr, LDS out-stage for coalesced 16B writes.
//  - Chunk relaunch = global resync: bounds wg drift in t, so per-XCD weight
//    working set (WcP 512KB + <=7 U_t slices) stays L2-resident. xp chunk
//    footprint 29 MB stays L3-hot.
// ============================================================================

typedef unsigned short u16;
typedef unsigned int u32;
typedef __attribute__((ext_vector_type(8))) short bf16x8;
typedef __attribute__((ext_vector_type(4))) float f32x4;

#define T_STEPS 49
#define CT 7                 // timesteps per chunk (49 = 7*7)
#define OUT_ROW 12544        // 49*256
#define STASH_COLS 160       // gate-weight cols resident in LDS

// rec3 dynamic-LDS layout (bytes)
#define OFF_CB   84480       // u16[16][264]  (after wLds u16[160][264])
#define OFF_SB   92928       // u16[16][264]
#define OFF_CF   101376      // f32[8][256]
#define OFF_Z    109568      // f32[8][1024]
#define OFF_H    142336      // f32[8][256]
#define REC_SMEM 150528

// xproj3 dynamic-LDS layout
#define OFF_OST  16896       // after aLds u16[32][264]
#define XP_SMEM  82944

__device__ __forceinline__ u16 f2b(float f) {
  u32 u = __float_as_uint(f);
  u += 0x7fffu + ((u >> 16) & 1u); // RNE
  return (u16)(u >> 16);
}
__device__ __forceinline__ float b2f(u16 h) { return __uint_as_float(((u32)h) << 16); }
__device__ __forceinline__ float sigm(float z) { return 1.0f / (1.0f + __expf(-z)); }
__device__ __forceinline__ float tanh_f(float z) {
  float e = __expf(-2.0f * fabsf(z));
  float r = (1.0f - e) / (1.0f + e);
  return __builtin_copysignf(r, z);
}

// ---------------------------------------------------------------------------
// Pack weights: WcP[n][k] = W_g[k][u], WxP[n][k] = W_g[256+k][u]; n=g*256+u.
__global__ void pack_w(const float* __restrict__ Wf, const float* __restrict__ Wi,
                       const float* __restrict__ Wc, const float* __restrict__ Wo,
                       u16* __restrict__ WcP, u16* __restrict__ WxP) {
  int n = blockIdx.x, k = threadIdx.x;
  int g = n >> 8, u = n & 255;
  const float* W = (g == 0) ? Wf : (g == 1) ? Wi : (g == 2) ? Wc : Wo;
  WcP[n * 256 + k] = f2b(W[k * 256 + u]);
  WxP[n * 256 + k] = f2b(W[(256 + k) * 256 + u]);
}

// ---------------------------------------------------------------------------
// U pack, Q read once. grid 256 blocks (jp) x 256 thr (j).
__global__ void pack_u2(const float* __restrict__ Q, u16* __restrict__ UP) {
  int jp = blockIdx.x, j = threadIdx.x;
  float q[9];
#pragma unroll
  for (int k = 0; k < 9; ++k) q[k] = Q[j * 2304 + jp * 9 + k];
  const float SQ2 = 1.41421356237f;
  for (int t = 0; t < T_STEPS; ++t) {
    float tv = (float)t / 48.0f;
    float acc = q[0];
#pragma unroll
    for (int i = 1; i <= 4; ++i) {
      float ang = 6.283185307179586f * (float)i * tv;
      acc += SQ2 * (sinf(ang) * q[2 * i - 1] + cosf(ang) * q[2 * i]);
    }
    UP[t * 65536 + jp * 256 + j] = f2b(acc);
  }
}

// ---------------------------------------------------------------------------
// xproj3: xp[m][n], m = b*CT + tt (chunk-local), n = g*256+u.
// 32 rows/wg, 512 thr (8 waves, wave w -> cols w*128..+127).
__global__ __launch_bounds__(512) void xproj3(const float* __restrict__ x,
                                              const u16* __restrict__ WxP,
                                              u16* __restrict__ xp, int t0) {
  extern __shared__ char smem[];
  u16(*aLds)[264] = (u16(*)[264])smem;
  u16(*oSt)[1032] = (u16(*)[1032])(smem + OFF_OST);
  int tid = threadIdx.x;
  int m0 = blockIdx.x * 32;
  // stage 32 rows x 256 fp32 -> bf16
#pragma unroll
  for (int it = 0; it < 4; ++it) {
    int fid = it * 512 + tid; // float4 index
    int r = fid >> 6, k4 = fid & 63;
    int g = m0 + r;
    int b = g / CT, tt = g - b * CT;
    float4 v = *(const float4*)&x[((size_t)b * T_STEPS + t0 + tt) * 256 + k4 * 4];
    u16 tmp[4] = {f2b(v.x), f2b(v.y), f2b(v.z), f2b(v.w)};
    *(uint2*)&aLds[r][k4 * 4] = *(uint2*)tmp;
  }
  __syncthreads();
  int w = tid >> 6, l = tid & 63, l15 = l & 15, quad = l >> 4;
#pragma unroll 1
  for (int c8 = 0; c8 < 8; ++c8) {
    int col = w * 128 + c8 * 16 + l15;
    bf16x8 bf[8];
    const u16* bp = WxP + (size_t)col * 256 + quad * 8;
#pragma unroll
    for (int ks = 0; ks < 8; ++ks) bf[ks] = *(const bf16x8*)(bp + ks * 32);
#pragma unroll
    for (int rt = 0; rt < 2; ++rt) {
      f32x4 acc = {0.f, 0.f, 0.f, 0.f};
#pragma unroll
      for (int ks = 0; ks < 8; ++ks) {
        bf16x8 a = *(const bf16x8*)&aLds[rt * 16 + l15][ks * 32 + quad * 8];
        acc = __builtin_amdgcn_mfma_f32_16x16x32_bf16(a, bf[ks], acc, 0, 0, 0);
      }
#pragma unroll
      for (int i = 0; i < 4; ++i) oSt[rt * 16 + quad * 4 + i][col] = f2b(acc[i]);
    }
  }
  __syncthreads();
  // coalesced write: 32 rows x 1024 u16 = 4096 16B-chunks = 512 thr x 8 iters
#pragma unroll
  for (int j = 0; j < 8; ++j) {
    int e = (j * 512 + tid) * 8; // u16 element offset
    int r = e >> 10, c = e & 1023;
    *(uint4*)&xp[(size_t)(m0 + r) * 1024 + c] = *(const uint4*)&oSt[r][c];
  }
}

// ---------------------------------------------------------------------------
// rec3: one 7-step chunk; wg = 8 batch rows, no inter-wg communication.
__global__ __launch_bounds__(512) void rec3(const u16* __restrict__ WcP,
                                            const u16* __restrict__ UP,
                                            const u16* __restrict__ xp,
                                            float* __restrict__ out,
                                            float* __restrict__ cstate,
                                            int tA) {
  extern __shared__ char smem[];
  u16(*wLds)[264] = (u16(*)[264])smem;
  u16(*cB)[264] = (u16(*)[264])(smem + OFF_CB);
  u16(*sB)[264] = (u16(*)[264])(smem + OFF_SB);
  float(*cF)[256] = (float(*)[256])(smem + OFF_CF);
  float(*Z)[1024] = (float(*)[1024])(smem + OFF_Z);
  float(*hS)[256] = (float(*)[256])(smem + OFF_H);

  int tid = threadIdx.x;
  int b0 = blockIdx.x * 8;

  // stash gate-weight cols 0..STASH_COLS-1 (once per launch)
  for (int c = tid; c < STASH_COLS * 32; c += 512) {
    int col = c >> 5, koff = (c & 31) * 8;
    *(uint4*)&wLds[col][koff] = *(const uint4*)&WcP[(size_t)col * 256 + koff];
  }
  for (int i = tid; i < 16 * 264; i += 512) {
    ((u16*)cB)[i] = 0;
    ((u16*)sB)[i] = 0;
  }
  for (int i = tid; i < 2048; i += 512) {
    int r = i >> 8, u = i & 255;
    float c0 = (tA == 0) ? 0.0f : cstate[(size_t)(b0 + r) * 256 + u];
    cF[r][u] = c0;
    cB[r][u] = f2b(c0);
  }
  __syncthreads();

  int w = tid >> 6, l = tid & 63, l15 = l & 15, quad = l >> 4;

#pragma unroll 1
  for (int tt = 0; tt < CT; ++tt) {
    int t = tA + tt;
    // xp prefetch (coalesced 2B/lane per gate)
    float xv[4][4];
#pragma unroll
    for (int p = 0; p < 4; ++p) {
      int item = tid + p * 512, r = item >> 8, u = item & 255;
      const u16* xb = xp + ((size_t)(b0 + r) * CT + tt) * 1024 + u;
#pragma unroll
      for (int g = 0; g < 4; ++g) xv[p][g] = b2f(xb[g * 256]);
    }
    if (t > 0) {
      // gate GEMM: wave w -> cols w*128..+127 (8 tiles), K=256
      bf16x8 af[8];
#pragma unroll
      for (int ks = 0; ks < 8; ++ks)
        af[ks] = *(const bf16x8*)&cB[l15][ks * 32 + quad * 8];
#pragma unroll
      for (int c8 = 0; c8 < 8; ++c8) {
        int tb = w * 128 + c8 * 16;
        f32x4 acc = {0.f, 0.f, 0.f, 0.f};
        if (tb < STASH_COLS) { // wave-uniform branch (LDS-stashed cols)
          const u16* bp = &wLds[tb + l15][quad * 8];
#pragma unroll
          for (int ks = 0; ks < 8; ++ks)
            acc = __builtin_amdgcn_mfma_f32_16x16x32_bf16(
                af[ks], *(const bf16x8*)(bp + ks * 32), acc, 0, 0, 0);
        } else {
          const u16* bp = WcP + (size_t)(tb + l15) * 256 + quad * 8;
#pragma unroll
          for (int ks = 0; ks < 8; ++ks)
            acc = __builtin_amdgcn_mfma_f32_16x16x32_bf16(
                af[ks], *(const bf16x8*)(bp + ks * 32), acc, 0, 0, 0);
        }
        if (quad < 2) {
          int col = tb + l15;
#pragma unroll
          for (int i = 0; i < 4; ++i) Z[quad * 4 + i][col] = acc[i];
        }
      }
      __syncthreads(); // B1: Z visible
    }
    // elementwise, fp32
#pragma unroll
    for (int p = 0; p < 4; ++p) {
      int item = tid + p * 512, r = item >> 8, u = item & 255;
      float zf = xv[p][0], zi = xv[p][1], zg = xv[p][2], zo = xv[p][3];
      if (t > 0) {
        zf += Z[r][u];
        zi += Z[r][256 + u];
        zg += Z[r][512 + u];
        zo += Z[r][768 + u];
      }
      float f = sigm(zf), ig = sigm(zi), gg = sigm(zg), o = tanh_f(zo);
      float cn = ig * gg + f * cF[r][u];
      cF[r][u] = cn;
      cB[r][u] = f2b(cn);
      sB[r][u] = f2b(o * tanh_f(cn));
    }
    __syncthreads(); // B2: cB/sB visible
    // proj GEMM: wave w -> cols w*32..+31 (2 tiles), B from UP (L2-hot)
    bf16x8 sf[8];
#pragma unroll
    for (int ks = 0; ks < 8; ++ks)
      sf[ks] = *(const bf16x8*)&sB[l15][ks * 32 + quad * 8];
#pragma unroll
    for (int c2 = 0; c2 < 2; ++c2) {
      f32x4 acc = {0.f, 0.f, 0.f, 0.f};
      const u16* up = UP + (size_t)t * 65536 + (size_t)(w * 32 + c2 * 16 + l15) * 256 + quad * 8;
#pragma unroll
      for (int ks = 0; ks < 8; ++ks)
        acc = __builtin_amdgcn_mfma_f32_16x16x32_bf16(
            sf[ks], *(const bf16x8*)(up + ks * 32), acc, 0, 0, 0);
      if (quad < 2) {
        int col = w * 32 + c2 * 16 + l15;
#pragma unroll
        for (int i = 0; i < 4; ++i) hS[quad * 4 + i][col] = tanh_f(acc[i]);
      }
    }
    __syncthreads(); // B3: hS visible
    // coalesced out write: 8 rows x 1KB fp32 runs (full-line writebacks)
    {
      int r = tid >> 6, c = (tid & 63) * 4;
      float4 v = *(const float4*)&hS[r][c];
      *(float4*)&out[(size_t)(b0 + r) * OUT_ROW + (size_t)t * 256 + c] = v;
    }
  }
  if (tA + CT < T_STEPS) {
    for (int i = tid; i < 2048; i += 512) {
      int r = i >> 8, u = i & 255;
      cstate[(size_t)(b0 + r) * 256 + u] = cF[r][u];
    }
  }
}

// ---------------------------------------------------------------------------
extern "C" void kernel_launch(void* const* d_in, const int* in_sizes, int n_in,
                              void* d_out, int out_size, void* d_ws, size_t ws_size,
                              hipStream_t stream) {
  const float* x = (const float*)d_in[0];
  const float* Wf = (const float*)d_in[1];
  const float* Wi = (const float*)d_in[2];
  const float* Wc = (const float*)d_in[3];
  const float* Wo = (const float*)d_in[4];
  const float* Q = (const float*)d_in[5];
  float* out = (float*)d_out;

  char* p = (char*)d_ws;
  u16* WcP = (u16*)p;     p += (size_t)1024 * 256 * 2;     // 512 KB
  u16* WxP = (u16*)p;     p += (size_t)1024 * 256 * 2;     // 512 KB
  u16* UP = (u16*)p;      p += (size_t)49 * 65536 * 2;     // 6.13 MB
  float* cstate = (float*)p; p += (size_t)2048 * 256 * 4;  // 2 MB
  u16* xp = (u16*)p;      // 2048*7*1024*2 = 29.4 MB (chunk-local)

  hipFuncSetAttribute((const void*)rec3, hipFuncAttributeMaxDynamicSharedMemorySize,
                      REC_SMEM);
  hipFuncSetAttribute((const void*)xproj3, hipFuncAttributeMaxDynamicSharedMemorySize,
                      XP_SMEM);

  pack_w<<<dim3(1024), dim3(256), 0, stream>>>(Wf, Wi, Wc, Wo, WcP, WxP);
  pack_u2<<<dim3(256), dim3(256), 0, stream>>>(Q, UP);

  for (int ch = 0; ch < 7; ++ch) {
    int t0 = ch * CT;
    xproj3<<<dim3(448), dim3(512), XP_SMEM, stream>>>(x, WxP, xp, t0);
    rec3<<<dim3(256), dim3(512), REC_SMEM, stream>>>(WcP, UP, xp, out, cstate, t0);
  }
}